// Round 1
// baseline (176.517 us; speedup 1.0000x reference)
//
#include <hip/hip_runtime.h>

// Problem: B=4, H=16, S=2048, D=64
//   scores = Q K^T / 8 ; attn = tanh(0.3*scores) ; out = attn V   (mask unused)
// Strategy: bf16 MFMA (16x16x32), QT=128 rows per block, KT=64 per iter,
//           4 waves/block, P via LDS round-trip, O accumulated in registers.

constexpr int S_LEN = 2048;
constexpr int DIM   = 64;
constexpr int QT    = 128;
constexpr int KT    = 64;

// tanh(0.3 * s / 8) = 1 - 2/(exp2(s * 2*log2(e)*0.0375) + 1)
constexpr float C_EXP2 = 0.10820212528f; // 0.075 * log2(e) * ... = 2*1.44269504*0.0375

typedef __bf16 bf16_t;
typedef bf16_t bf16x8 __attribute__((ext_vector_type(8)));
typedef float  f32x4  __attribute__((ext_vector_type(4)));

__device__ inline bf16x8 to_bf8(float4 a, float4 b) {
    bf16x8 v;
    v[0] = (bf16_t)a.x; v[1] = (bf16_t)a.y; v[2] = (bf16_t)a.z; v[3] = (bf16_t)a.w;
    v[4] = (bf16_t)b.x; v[5] = (bf16_t)b.y; v[6] = (bf16_t)b.z; v[7] = (bf16_t)b.w;
    return v;
}

__global__ __launch_bounds__(256) void tanh_attn_kernel(
    const float* __restrict__ Q, const float* __restrict__ K,
    const float* __restrict__ V, float* __restrict__ O)
{
    const int tid  = threadIdx.x;
    const int lane = tid & 63;
    const int wv   = tid >> 6;          // wave id 0..3
    const int lr   = lane & 15;         // fragment row/col lane index
    const int lg   = lane >> 4;         // k-chunk group 0..3

    const int bid   = blockIdx.x;
    const int qtile = bid & 15;         // S/QT = 16
    const int bh    = bid >> 4;         // 0..63
    const int base  = bh * (S_LEN * DIM);
    const int q0    = qtile * QT;

    // LDS: Ql doubles as per-wave P buffer (each wave only touches its own
    // 32-row slice for both Q fragments and P).
    __shared__ bf16_t Ql[QT * DIM];     // 16 KB, swizzled rows
    __shared__ bf16_t Kl[KT * DIM];     // 8 KB,  [kv][d] swizzled
    __shared__ bf16_t Vt[DIM * KT];     // 8 KB,  [d][kv] swizzled (V transposed)

    // ---- stage Q tile (f32 -> bf16, XOR swizzle (row&7)<<3 on 8-elem chunks) ----
    #pragma unroll
    for (int it = 0; it < 4; ++it) {
        int cid = tid + it * 256;           // 0..1023 chunk id
        int r   = cid >> 3;
        int c8  = (cid & 7) * 8;
        const float* src = Q + base + (q0 + r) * DIM + c8;
        float4 a = *(const float4*)src;
        float4 b = *(const float4*)(src + 4);
        *(bf16x8*)&Ql[r * DIM + (c8 ^ ((r & 7) << 3))] = to_bf8(a, b);
    }
    __syncthreads();

    // ---- hoist Q A-fragments into registers (constant across K loop) ----
    // A-frag: lane holds row (lr), k-elems lg*8..lg*8+7 (contiguous)
    bf16x8 qa[2][2];
    #pragma unroll
    for (int rt = 0; rt < 2; ++rt)
        #pragma unroll
        for (int ks = 0; ks < 2; ++ks) {
            int r = wv * 32 + rt * 16 + lr;
            int c = ks * 32 + lg * 8;
            qa[rt][ks] = *(const bf16x8*)&Ql[r * DIM + (c ^ ((r & 7) << 3))];
        }
    __syncthreads();

    f32x4 oacc[2][4] = {};   // O accumulator: 2 row-tiles x 4 d-tiles x 4 f32

    bf16_t* Pl = Ql + wv * (32 * DIM);  // per-wave P slice [32][64] swizzled

    for (int kt = 0; kt < S_LEN / KT; ++kt) {
        const int k0 = kt * KT;

        // ---- stage K tile [kv][d] ----
        #pragma unroll
        for (int it = 0; it < 2; ++it) {
            int cid = tid + it * 256;       // 0..511
            int r   = cid >> 3;
            int c8  = (cid & 7) * 8;
            const float* src = K + base + (k0 + r) * DIM + c8;
            float4 a = *(const float4*)src;
            float4 b = *(const float4*)(src + 4);
            *(bf16x8*)&Kl[r * DIM + (c8 ^ ((r & 7) << 3))] = to_bf8(a, b);
        }
        // ---- stage V tile transposed: Vt[d][kv] ----
        // lane reads 8 f32 strided by DIM (each instr = coalesced 256B row),
        // packs kv-contiguous bf16x8, single b128 write.
        #pragma unroll
        for (int it = 0; it < 2; ++it) {
            int cid = tid + it * 256;       // 0..511
            int d   = cid & 63;
            int kv0 = (cid >> 6) * 8;
            const float* src = V + base + (k0 + kv0) * DIM + d;
            bf16x8 v;
            #pragma unroll
            for (int j = 0; j < 8; ++j) v[j] = (bf16_t)src[j * DIM];
            *(bf16x8*)&Vt[d * KT + (kv0 ^ ((d & 7) << 3))] = v;
        }
        __syncthreads();

        // ---- GEMM1: S = Q K^T  (per wave: 32q x 64kv) ----
        f32x4 sacc[2][4] = {};
        #pragma unroll
        for (int ct = 0; ct < 4; ++ct) {
            int r = ct * 16 + lr;           // kv row (B-frag col = lr)
            bf16x8 kb0 = *(const bf16x8*)&Kl[r * DIM + ((lg * 8)      ^ ((r & 7) << 3))];
            bf16x8 kb1 = *(const bf16x8*)&Kl[r * DIM + ((32 + lg * 8) ^ ((r & 7) << 3))];
            #pragma unroll
            for (int rt = 0; rt < 2; ++rt) {
                sacc[rt][ct] = __builtin_amdgcn_mfma_f32_16x16x32_bf16(qa[rt][0], kb0, sacc[rt][ct], 0, 0, 0);
                sacc[rt][ct] = __builtin_amdgcn_mfma_f32_16x16x32_bf16(qa[rt][1], kb1, sacc[rt][ct], 0, 0, 0);
            }
        }

        // ---- tanh + store P (bf16) into own LDS slice ----
        // C/D layout: row = lg*4 + j (within 16-tile), col = lr
        #pragma unroll
        for (int rt = 0; rt < 2; ++rt)
            #pragma unroll
            for (int ct = 0; ct < 4; ++ct)
                #pragma unroll
                for (int j = 0; j < 4; ++j) {
                    float t = __builtin_amdgcn_exp2f(sacc[rt][ct][j] * C_EXP2);
                    float p = 1.0f - 2.0f * __builtin_amdgcn_rcpf(t + 1.0f);
                    int q = rt * 16 + lg * 4 + j;
                    int c = ct * 16 + lr;
                    Pl[q * KT + (c ^ ((q & 7) << 3))] = (bf16_t)p;
                }

        // ---- load P A-fragments ----
        bf16x8 pa[2][2];
        #pragma unroll
        for (int rt = 0; rt < 2; ++rt)
            #pragma unroll
            for (int ks = 0; ks < 2; ++ks) {
                int r = rt * 16 + lr;
                pa[rt][ks] = *(const bf16x8*)&Pl[r * KT + ((ks * 32 + lg * 8) ^ ((r & 7) << 3))];
            }

        // ---- GEMM2: O += P V ----
        #pragma unroll
        for (int dt = 0; dt < 4; ++dt) {
            int d = dt * 16 + lr;           // output col = Vt row
            bf16x8 vb0 = *(const bf16x8*)&Vt[d * KT + ((lg * 8)      ^ ((d & 7) << 3))];
            bf16x8 vb1 = *(const bf16x8*)&Vt[d * KT + ((32 + lg * 8) ^ ((d & 7) << 3))];
            #pragma unroll
            for (int rt = 0; rt < 2; ++rt) {
                oacc[rt][dt] = __builtin_amdgcn_mfma_f32_16x16x32_bf16(pa[rt][0], vb0, oacc[rt][dt], 0, 0, 0);
                oacc[rt][dt] = __builtin_amdgcn_mfma_f32_16x16x32_bf16(pa[rt][1], vb1, oacc[rt][dt], 0, 0, 0);
            }
        }
        __syncthreads();
    }

    // ---- epilogue: write O (f32) ----
    #pragma unroll
    for (int rt = 0; rt < 2; ++rt)
        #pragma unroll
        for (int dt = 0; dt < 4; ++dt)
            #pragma unroll
            for (int j = 0; j < 4; ++j) {
                int q = q0 + wv * 32 + rt * 16 + lg * 4 + j;
                int d = dt * 16 + lr;
                O[base + q * DIM + d] = oacc[rt][dt][j];
            }
}

extern "C" void kernel_launch(void* const* d_in, const int* in_sizes, int n_in,
                              void* d_out, int out_size, void* d_ws, size_t ws_size,
                              hipStream_t stream) {
    const float* Q = (const float*)d_in[0];
    const float* K = (const float*)d_in[1];
    const float* V = (const float*)d_in[2];
    float* O = (float*)d_out;
    // grid: 64 heads * 16 q-tiles; consecutive blocks share a head's K/V (L2 reuse)
    dim3 grid(64 * (S_LEN / QT));
    dim3 block(256);
    hipLaunchKernelGGL(tanh_attn_kernel, grid, block, 0, stream, Q, K, V, O);
}

// Round 2
// 109.561 us; speedup vs baseline: 1.6111x; 1.6111x over previous
//
#include <hip/hip_runtime.h>

// Problem: B=4, H=16, S=2048, D=64
//   scores = Q K^T / 8 ; attn = tanh(0.3*scores) ; out = attn V   (mask unused)
// Round 2: QT=256 (8 waves/block, halves K/V restaging), swapped GEMM1
//          (S^T = K·Q^T) so P stores pack to ds_write_b64, XCD-aware swizzle.

constexpr int S_LEN = 2048;
constexpr int DIM   = 64;
constexpr int QT    = 256;
constexpr int KT    = 64;

// tanh(0.3 * s / 8): tanh(a*x) = 1 - 2/(exp2(2*a*x*log2e)+1); 2*0.0375*log2(e)
constexpr float C_EXP2 = 0.10820212528f;

typedef __bf16 bf16_t;
typedef bf16_t bf16x4 __attribute__((ext_vector_type(4)));
typedef bf16_t bf16x8 __attribute__((ext_vector_type(8)));
typedef float  f32x4  __attribute__((ext_vector_type(4)));

__device__ inline bf16x8 to_bf8(float4 a, float4 b) {
    bf16x8 v;
    v[0] = (bf16_t)a.x; v[1] = (bf16_t)a.y; v[2] = (bf16_t)a.z; v[3] = (bf16_t)a.w;
    v[4] = (bf16_t)b.x; v[5] = (bf16_t)b.y; v[6] = (bf16_t)b.z; v[7] = (bf16_t)b.w;
    return v;
}

__global__ __launch_bounds__(512, 4) void tanh_attn_kernel(
    const float* __restrict__ Q, const float* __restrict__ K,
    const float* __restrict__ V, float* __restrict__ O)
{
    const int tid  = threadIdx.x;
    const int lane = tid & 63;
    const int wv   = tid >> 6;          // wave id 0..7
    const int lr   = lane & 15;
    const int lg   = lane >> 4;

    // XCD-aware swizzle: grid=512, 512%8==0, so simple bijective remap.
    const int nwg = gridDim.x;
    const int bid = (blockIdx.x & 7) * (nwg >> 3) + (blockIdx.x >> 3);
    const int qtile = bid & 7;          // S/QT = 8
    const int bh    = bid >> 3;         // 0..63
    const int base  = bh * (S_LEN * DIM);
    const int q0    = qtile * QT;

    __shared__ bf16_t Ql[QT * DIM];     // 32 KB (doubles as per-wave P buffer)
    __shared__ bf16_t Kl[KT * DIM];     // 8 KB, [kv][d] swizzled
    __shared__ bf16_t Vt[DIM * KT];     // 8 KB, [d][kv] swizzled (V transposed)

    // ---- stage Q tile (f32 -> bf16, XOR swizzle (row&7)<<3 on 8-elem chunks) ----
    #pragma unroll
    for (int it = 0; it < 4; ++it) {
        int cid = tid + it * 512;           // 0..2047
        int r   = cid >> 3;
        int c8  = (cid & 7) * 8;
        const float* src = Q + base + (q0 + r) * DIM + c8;
        float4 a = *(const float4*)src;
        float4 b = *(const float4*)(src + 4);
        *(bf16x8*)&Ql[r * DIM + (c8 ^ ((r & 7) << 3))] = to_bf8(a, b);
    }
    __syncthreads();

    // ---- hoist Q B-fragments into registers (constant across K loop) ----
    bf16x8 qa[2][2];
    #pragma unroll
    for (int rt = 0; rt < 2; ++rt)
        #pragma unroll
        for (int ks = 0; ks < 2; ++ks) {
            int r = wv * 32 + rt * 16 + lr;
            int c = ks * 32 + lg * 8;
            qa[rt][ks] = *(const bf16x8*)&Ql[r * DIM + (c ^ ((r & 7) << 3))];
        }
    __syncthreads();

    f32x4 oacc[2][4] = {};

    bf16_t* Pl = Ql + wv * (32 * KT);   // per-wave P slice [32][64] swizzled

    for (int kt = 0; kt < S_LEN / KT; ++kt) {
        const int k0 = kt * KT;

        // ---- stage K tile [kv][d]: 512 threads x one 8-elem chunk ----
        {
            int r   = tid >> 3;             // 0..63
            int c8  = (tid & 7) * 8;
            const float* src = K + base + (k0 + r) * DIM + c8;
            float4 a = *(const float4*)src;
            float4 b = *(const float4*)(src + 4);
            *(bf16x8*)&Kl[r * DIM + (c8 ^ ((r & 7) << 3))] = to_bf8(a, b);
        }
        // ---- stage V transposed: Vt[d][kv]; lane reads 8 f32 strided by DIM ----
        {
            int d   = tid & 63;
            int kv0 = (tid >> 6) * 8;
            const float* src = V + base + (k0 + kv0) * DIM + d;
            bf16x8 v;
            #pragma unroll
            for (int j = 0; j < 8; ++j) v[j] = (bf16_t)src[j * DIM];
            *(bf16x8*)&Vt[d * KT + (kv0 ^ ((d & 7) << 3))] = v;
        }
        __syncthreads();

        // ---- GEMM1 (swapped): S^T = K · Q^T; D[m=kv][n=q] ----
        // A-frag = K rows (kv=ct*16+lr, k=d), B-frag = Q rows (q, k=d) == qa.
        f32x4 sacc[2][4] = {};
        #pragma unroll
        for (int ct = 0; ct < 4; ++ct) {
            int r = ct * 16 + lr;           // kv
            bf16x8 kb0 = *(const bf16x8*)&Kl[r * DIM + ((lg * 8)      ^ ((r & 7) << 3))];
            bf16x8 kb1 = *(const bf16x8*)&Kl[r * DIM + ((32 + lg * 8) ^ ((r & 7) << 3))];
            #pragma unroll
            for (int rt = 0; rt < 2; ++rt) {
                sacc[rt][ct] = __builtin_amdgcn_mfma_f32_16x16x32_bf16(kb0, qa[rt][0], sacc[rt][ct], 0, 0, 0);
                sacc[rt][ct] = __builtin_amdgcn_mfma_f32_16x16x32_bf16(kb1, qa[rt][1], sacc[rt][ct], 0, 0, 0);
            }
        }

        // ---- tanh + packed P store: lane holds q=rt*16+lr, kv=ct*16+lg*4+j ----
        // j is kv-contiguous -> pack 4 bf16 -> one ds_write_b64 per (rt,ct).
        #pragma unroll
        for (int rt = 0; rt < 2; ++rt)
            #pragma unroll
            for (int ct = 0; ct < 4; ++ct) {
                bf16x4 p4;
                #pragma unroll
                for (int j = 0; j < 4; ++j) {
                    float t = __builtin_amdgcn_exp2f(sacc[rt][ct][j] * C_EXP2);
                    p4[j] = (bf16_t)(1.0f - 2.0f * __builtin_amdgcn_rcpf(t + 1.0f));
                }
                int q  = rt * 16 + lr;
                int c0 = ct * 16 + lg * 4;
                *(bf16x4*)&Pl[q * KT + (c0 ^ ((q & 7) << 3))] = p4;
            }

        // ---- load P A-fragments (same-wave LDS, no barrier needed) ----
        bf16x8 pa[2][2];
        #pragma unroll
        for (int rt = 0; rt < 2; ++rt)
            #pragma unroll
            for (int ks = 0; ks < 2; ++ks) {
                int r = rt * 16 + lr;
                pa[rt][ks] = *(const bf16x8*)&Pl[r * KT + ((ks * 32 + lg * 8) ^ ((r & 7) << 3))];
            }

        // ---- GEMM2: O += P · V ----
        #pragma unroll
        for (int dt = 0; dt < 4; ++dt) {
            int d = dt * 16 + lr;
            bf16x8 vb0 = *(const bf16x8*)&Vt[d * KT + ((lg * 8)      ^ ((d & 7) << 3))];
            bf16x8 vb1 = *(const bf16x8*)&Vt[d * KT + ((32 + lg * 8) ^ ((d & 7) << 3))];
            #pragma unroll
            for (int rt = 0; rt < 2; ++rt) {
                oacc[rt][dt] = __builtin_amdgcn_mfma_f32_16x16x32_bf16(pa[rt][0], vb0, oacc[rt][dt], 0, 0, 0);
                oacc[rt][dt] = __builtin_amdgcn_mfma_f32_16x16x32_bf16(pa[rt][1], vb1, oacc[rt][dt], 0, 0, 0);
            }
        }
        __syncthreads();
    }

    // ---- epilogue: write O (f32) ----
    #pragma unroll
    for (int rt = 0; rt < 2; ++rt)
        #pragma unroll
        for (int dt = 0; dt < 4; ++dt)
            #pragma unroll
            for (int j = 0; j < 4; ++j) {
                int q = q0 + wv * 32 + rt * 16 + lg * 4 + j;
                int d = dt * 16 + lr;
                O[base + q * DIM + d] = oacc[rt][dt][j];
            }
}

extern "C" void kernel_launch(void* const* d_in, const int* in_sizes, int n_in,
                              void* d_out, int out_size, void* d_ws, size_t ws_size,
                              hipStream_t stream) {
    const float* Q = (const float*)d_in[0];
    const float* K = (const float*)d_in[1];
    const float* V = (const float*)d_in[2];
    float* O = (float*)d_out;
    dim3 grid(64 * (S_LEN / QT));   // 512 blocks
    dim3 block(512);
    hipLaunchKernelGGL(tanh_attn_kernel, grid, block, 0, stream, Q, K, V, O);
}